// Round 13
// baseline (196.600 us; speedup 1.0000x reference)
//
#include <hip/hip_runtime.h>

#define F_DIM   256
#define OVFCAP  8192
#define MAXBUCK 1024
#define BCAP    2560     // bucket capacity (mean 2048, +11 sigma); MUST be <= 512*5
#define P1_TILE 8192     // edges per bucket-build block (1024 thr x 8)
#define WINB    12       // log2 window cols: 4096 cols * 512 B = 2 MB << 4 MB L2/XCD
#define RCAP2   12       // per-row per-pass LDS slots (lambda ~2.5 at npass=13)
#define ELLK    64       // fallback path

struct OvfEdge { int r, c; float v; };

__device__ __forceinline__ unsigned short f32_to_bf16(float x) {
    unsigned u = __float_as_uint(x);
    unsigned r = (u + 0x7FFFu + ((u >> 16) & 1u)) >> 16;  // RNE
    return (unsigned short)r;
}

__device__ __forceinline__ void gfma(unsigned e, int lane,
                                     const unsigned short* __restrict__ mb, float4& acc) {
    int   col = (int)(e >> 16);
    float v   = __uint_as_float((e & 0xFFFFu) << 16);
    ushort4 m = ((const ushort4*)(mb + ((long long)col << 8)))[lane];
    acc.x += v * __uint_as_float((unsigned)m.x << 16);
    acc.y += v * __uint_as_float((unsigned)m.y << 16);
    acc.z += v * __uint_as_float((unsigned)m.z << 16);
    acc.w += v * __uint_as_float((unsigned)m.w << 16);
}

// ---------- standalone cvt (fallback path B) ----------
__global__ void cvt_kernel(const float* __restrict__ src,
                           unsigned short* __restrict__ dst, int n4) {
    int t = blockIdx.x * blockDim.x + threadIdx.x;
    if (t >= n4) return;
    float4 f = ((const float4*)src)[t];
    ushort4 o;
    o.x = f32_to_bf16(f.x); o.y = f32_to_bf16(f.y);
    o.z = f32_to_bf16(f.z); o.w = f32_to_bf16(f.w);
    ((ushort4*)dst)[t] = o;
}

// ---------- fused build: blocks [0,p1blocks) bucket edges; rest convert mat_2 ----------
__global__ void __launch_bounds__(1024)
build_kernel(const int* __restrict__ rows, const int* __restrict__ cols,
             const float* __restrict__ vals,
             const float* __restrict__ mat2, unsigned short* __restrict__ mb, int n4,
             int* __restrict__ gcur, int2* __restrict__ ebuf,
             int* __restrict__ ovfcnt, OvfEdge* __restrict__ ovf,
             int E, int nbuck, int p1blocks) {
    __shared__ int s_cnt[MAXBUCK];
    __shared__ int s_base[MAXBUCK];
    __shared__ int s_cur[MAXBUCK];
    const int t = threadIdx.x;
    const int bid = blockIdx.x;

    if (bid >= p1blocks) {                       // ---- cvt part ----
        int i = (bid - p1blocks) * 1024 + t;
        if (i < n4) {
            float4 f = ((const float4*)mat2)[i];
            ushort4 o;
            o.x = f32_to_bf16(f.x); o.y = f32_to_bf16(f.y);
            o.z = f32_to_bf16(f.z); o.w = f32_to_bf16(f.w);
            ((ushort4*)mb)[i] = o;
        }
        return;
    }

    // ---- bucket part ----
    for (int i = t; i < nbuck; i += 1024) { s_cnt[i] = 0; s_cur[i] = 0; }
    __syncthreads();

    const long long e0 = (long long)bid * P1_TILE;
    int4 r4[2], c4[2]; float4 v4[2];
    #pragma unroll
    for (int k = 0; k < 2; ++k) {
        long long i = e0 + (long long)k * 4096 + (long long)t * 4;
        if (i + 3 < E) {
            r4[k] = *(const int4*)(rows + i);
            c4[k] = *(const int4*)(cols + i);
            v4[k] = *(const float4*)(vals + i);
        } else {
            r4[k] = make_int4(-1, -1, -1, -1);
            c4[k] = make_int4(0, 0, 0, 0);
            v4[k] = make_float4(0.f, 0.f, 0.f, 0.f);
            #pragma unroll
            for (int j = 0; j < 4; ++j) {
                long long ii = i + j;
                if (ii < E) {
                    (&r4[k].x)[j] = rows[ii];
                    (&c4[k].x)[j] = cols[ii];
                    (&v4[k].x)[j] = vals[ii];
                }
            }
        }
        #pragma unroll
        for (int j = 0; j < 4; ++j) {
            int rr = (&r4[k].x)[j];
            if (rr >= 0) atomicAdd(&s_cnt[rr >> 6], 1);   // LDS
        }
    }
    __syncthreads();
    for (int i = t; i < nbuck; i += 1024) {
        int c_ = s_cnt[i];
        s_base[i] = c_ ? atomicAdd(&gcur[i], c_) : 0;     // 1 global atomic per (block,bucket)
    }
    __syncthreads();
    #pragma unroll
    for (int k = 0; k < 2; ++k) {
        #pragma unroll
        for (int j = 0; j < 4; ++j) {
            int rr = (&r4[k].x)[j];
            if (rr < 0) continue;
            int cc = (&c4[k].x)[j];
            float vv = (&v4[k].x)[j];
            int b = rr >> 6;
            int sl = s_base[b] + atomicAdd(&s_cur[b], 1); // LDS
            if (sl < BCAP) {
                ebuf[(long long)b * BCAP + sl] =
                    make_int2((int)(((unsigned)cc << 16) | f32_to_bf16(vv)), rr & 63);
            } else {
                int o = atomicAdd(ovfcnt, 1);
                if (o < OVFCAP) { ovf[o].r = rr; ovf[o].c = cc; ovf[o].v = vv; }
            }
        }
    }
}

// ---------- Phase 2: one block per 64-row bucket.
// Edges live in registers (<=5/thread). Per pass (4096-col, 2MB L2 window):
// register-scan bins matching edges into a small double-buffered LDS ELL;
// bin(p+1) overlaps compute(p). Compute: half-wave rows, int4 (8xbf16)
// gathers batched x2, pad slots select window-base col. 1 barrier/pass.
// LDS ~7KB + VGPR<=64 -> 4 blocks/CU -> all buckets co-resident (no tail). ----------
__global__ void __launch_bounds__(512, 8)
spmm_pass_kernel(const int* __restrict__ gcur, const int2* __restrict__ ebuf,
                 const unsigned short* __restrict__ mb,
                 float* __restrict__ out, int N,
                 int* __restrict__ ovfcnt, OvfEdge* __restrict__ ovf) {
    __shared__ unsigned ell_s[2][64 * RCAP2];       // 6 KB
    __shared__ int cur_s[2][64];
    const int t = threadIdx.x, b = blockIdx.x;
    const int hw = t >> 5, fl = t & 31;             // half-wave id, lane in half
    const int npass = (N + (1 << WINB) - 1) >> WINB;
    const int cnt = min(gcur[b], BCAP);
    const int2* eb = ebuf + (long long)b * BCAP;

    if (t < 128) ((int*)cur_s)[t] = 0;

    // ---- load up to 5 strided edges into registers (512*5 = 2560 = BCAP) ----
    unsigned ecol[5]; int erow[5]; int nv = 0;
    #pragma unroll
    for (int k = 0; k < 5; ++k) {
        int j = t + k * 512;
        if (j < cnt) {
            int2 e = eb[j];
            ecol[nv] = (unsigned)e.x;
            erow[nv] = e.y;
            ++nv;
        }
    }
    __syncthreads();   // cur_s zeroed

    auto bin = [&](int p, int buf) {
        for (int k = 0; k < nv; ++k) {
            if ((int)(ecol[k] >> (16 + WINB)) == p) {
                int pos = atomicAdd(&cur_s[buf][erow[k]], 1);
                if (pos < RCAP2) {
                    ell_s[buf][erow[k] * RCAP2 + pos] = ecol[k];
                } else {
                    int o = atomicAdd(ovfcnt, 1);
                    if (o < OVFCAP) {
                        ovf[o].r = b * 64 + erow[k];
                        ovf[o].c = (int)(ecol[k] >> 16);
                        ovf[o].v = __uint_as_float((ecol[k] & 0xFFFFu) << 16);
                    }
                }
            }
        }
    };

    bin(0, 0);
    __syncthreads();

    float acc[4][8];
    #pragma unroll
    for (int r = 0; r < 4; ++r)
        #pragma unroll
        for (int q = 0; q < 8; ++q) acc[r][q] = 0.f;

    for (int p = 0; p < npass; ++p) {
        const int cur = p & 1, nxt = cur ^ 1;
        if (p + 1 < npass) bin(p + 1, nxt);         // overlaps gathers below

        const unsigned padv = (unsigned)p << (16 + WINB);   // col = window base, v = 0
        #pragma unroll
        for (int ri = 0; ri < 4; ++ri) {
            const int rr = hw + (ri << 4);          // half-wave hw owns rows hw, hw+16, +32, +48
            int deg = min(cur_s[cur][rr], RCAP2);
            int padded = (deg + 1) & ~1;
            for (int j = 0; j < padded; j += 2) {
                int4 m[2]; float v[2];
                #pragma unroll
                for (int k = 0; k < 2; ++k) {       // 2 independent 16B gathers
                    unsigned raw = ell_s[cur][rr * RCAP2 + j + k];   // stale-safe: selected below
                    unsigned e = (j + k < deg) ? raw : padv;
                    v[k] = __uint_as_float((e & 0xFFFFu) << 16);
                    m[k] = ((const int4*)(mb + ((long long)(e >> 16) << 8)))[fl];
                }
                #pragma unroll
                for (int k = 0; k < 2; ++k) {       // unpack 8 bf16 + FMA
                    acc[ri][0] += v[k] * __uint_as_float((unsigned)m[k].x << 16);
                    acc[ri][1] += v[k] * __uint_as_float((unsigned)m[k].x & 0xFFFF0000u);
                    acc[ri][2] += v[k] * __uint_as_float((unsigned)m[k].y << 16);
                    acc[ri][3] += v[k] * __uint_as_float((unsigned)m[k].y & 0xFFFF0000u);
                    acc[ri][4] += v[k] * __uint_as_float((unsigned)m[k].z << 16);
                    acc[ri][5] += v[k] * __uint_as_float((unsigned)m[k].z & 0xFFFF0000u);
                    acc[ri][6] += v[k] * __uint_as_float((unsigned)m[k].w << 16);
                    acc[ri][7] += v[k] * __uint_as_float((unsigned)m[k].w & 0xFFFF0000u);
                }
            }
            if (fl == 0) cur_s[cur][rr] = 0;        // recycle counter for pass p+2
        }
        __syncthreads();
    }

    // ---- epilogue: each half-wave stores its 4 rows (32B/lane) ----
    #pragma unroll
    for (int ri = 0; ri < 4; ++ri) {
        const int rr = hw + (ri << 4);
        long long gr = (long long)b * 64 + rr;
        if (gr < N) {
            float4* op = (float4*)(out + (gr << 8) + (fl << 3));
            op[0] = make_float4(acc[ri][0], acc[ri][1], acc[ri][2], acc[ri][3]);
            op[1] = make_float4(acc[ri][4], acc[ri][5], acc[ri][6], acc[ri][7]);
        }
    }
}

// ---------- overflow fixup (expected ~0): f32 atomics ----------
__global__ void ovf_kernel(const int* __restrict__ ovfcnt,
                           const OvfEdge* __restrict__ ovf,
                           const float* __restrict__ mat2,
                           float* __restrict__ out) {
    int cnt = min(*ovfcnt, OVFCAP);
    int lane = threadIdx.x & 63;
    int wid = threadIdx.x >> 6;
    for (int e = wid; e < cnt; e += 4) {
        OvfEdge ed = ovf[e];
        float4 m = ((const float4*)(mat2 + (long long)ed.c * F_DIM))[lane];
        float* dst = out + (long long)ed.r * F_DIM + lane * 4;
        unsafeAtomicAdd(dst + 0, ed.v * m.x);
        unsafeAtomicAdd(dst + 1, ed.v * m.y);
        unsafeAtomicAdd(dst + 2, ed.v * m.z);
        unsafeAtomicAdd(dst + 3, ed.v * m.w);
    }
}

// ---------- Fallback path B/C: global-cursor ELL (R5) ----------
__device__ __forceinline__ void scatter_one(int r, int c, float v,
                                            int* cursor, unsigned* ell,
                                            int* ovfcnt, OvfEdge* ovf) {
    int pos = atomicAdd(&cursor[r], 1);
    if (pos < ELLK) {
        ell[(long long)r * ELLK + pos] = ((unsigned)c << 16) | f32_to_bf16(v);
    } else {
        int o = atomicAdd(ovfcnt, 1);
        if (o < OVFCAP) { ovf[o].r = r; ovf[o].c = c; ovf[o].v = v; }
    }
}

__global__ void scatter_ell_kernel(const int* __restrict__ rows,
                                   const int* __restrict__ cols,
                                   const float* __restrict__ vals,
                                   int* __restrict__ cursor,
                                   unsigned* __restrict__ ell,
                                   int* __restrict__ ovfcnt,
                                   OvfEdge* __restrict__ ovf, int E) {
    int t = blockIdx.x * blockDim.x + threadIdx.x;
    int i0 = t * 4;
    if (i0 + 3 < E) {
        int4   r = *(const int4*)(rows + i0);
        int4   c = *(const int4*)(cols + i0);
        float4 v = *(const float4*)(vals + i0);
        scatter_one(r.x, c.x, v.x, cursor, ell, ovfcnt, ovf);
        scatter_one(r.y, c.y, v.y, cursor, ell, ovfcnt, ovf);
        scatter_one(r.z, c.z, v.z, cursor, ell, ovfcnt, ovf);
        scatter_one(r.w, c.w, v.w, cursor, ell, ovfcnt, ovf);
    } else {
        for (int i = i0; i < E; ++i)
            scatter_one(rows[i], cols[i], vals[i], cursor, ell, ovfcnt, ovf);
    }
}

template <bool BF16MAT>
__global__ void __launch_bounds__(256)
spmm_ell_kernel(const int* __restrict__ cursor,
                const unsigned* __restrict__ ell,
                const unsigned short* __restrict__ mb,
                const float* __restrict__ mat2,
                float* __restrict__ out, int N) {
    int wave = (int)(((long long)blockIdx.x * blockDim.x + threadIdx.x) >> 6);
    int lane = threadIdx.x & 63;
    if (wave >= N) return;
    int deg = min(cursor[wave], ELLK);
    unsigned pk = (lane < deg) ? ell[(long long)wave * ELLK + lane] : 0u;
    float4 acc = make_float4(0.f, 0.f, 0.f, 0.f);
    int padded = (deg + 7) & ~7;
    for (int j = 0; j < padded; j += 8) {
        #pragma unroll
        for (int k = 0; k < 8; ++k) {
            unsigned e = (unsigned)__shfl((int)pk, j + k);
            if (BF16MAT) {
                gfma(e, lane, mb, acc);
            } else {
                int   col = (int)(e >> 16);
                float v   = __uint_as_float((e & 0xFFFFu) << 16);
                float4 m = ((const float4*)(mat2 + ((long long)col << 8)))[lane];
                acc.x += v * m.x; acc.y += v * m.y;
                acc.z += v * m.z; acc.w += v * m.w;
            }
        }
    }
    ((float4*)(out + ((long long)wave << 8)))[lane] = acc;
}

// ---------- last resort: pure atomic SpMM ----------
__global__ void spmm_atomic_kernel(const int* __restrict__ rows,
                                   const int* __restrict__ cols,
                                   const float* __restrict__ vals,
                                   const float* __restrict__ mat2,
                                   float* __restrict__ out, int E) {
    long long gid = (long long)blockIdx.x * blockDim.x + threadIdx.x;
    long long e = gid >> 6;
    int q = (int)(gid & 63);
    if (e >= E) return;
    int r = rows[e]; int c = cols[e]; float v = vals[e];
    float4 m = ((const float4*)(mat2 + (long long)c * F_DIM))[q];
    float* dst = out + (long long)r * F_DIM + q * 4;
    unsafeAtomicAdd(dst + 0, v * m.x);
    unsafeAtomicAdd(dst + 1, v * m.y);
    unsafeAtomicAdd(dst + 2, v * m.z);
    unsafeAtomicAdd(dst + 3, v * m.w);
}

extern "C" void kernel_launch(void* const* d_in, const int* in_sizes, int n_in,
                              void* d_out, int out_size, void* d_ws, size_t ws_size,
                              hipStream_t stream) {
    const int*   indices = (const int*)d_in[0];
    const float* vals    = (const float*)d_in[1];
    const float* mat2    = (const float*)d_in[3];
    float*       out     = (float*)d_out;

    const int E  = in_sizes[1];
    const int N  = out_size / F_DIM;
    const int M2 = in_sizes[3];
    const int n4 = M2 / 4;
    const int* rows = indices;
    const int* cols = indices + E;
    const int nbuck = (N + 63) >> 6;

    auto align16 = [](size_t x) { return (x + 15) & ~(size_t)15; };
    char* ws = (char*)d_ws;

    // ---- Path A layout: bucket ----
    size_t o = 0;
    int* gcur    = (int*)(ws + o);
    int* ovfcntA = gcur + nbuck;
    o = align16(o + ((size_t)nbuck + 1) * 4);
    OvfEdge* ovfA = (OvfEdge*)(ws + o); o = align16(o + (size_t)OVFCAP * sizeof(OvfEdge));
    int2* ebuf = (int2*)(ws + o);       o = align16(o + (size_t)nbuck * BCAP * 8);
    unsigned short* mbA = (unsigned short*)(ws + o); o = align16(o + (size_t)M2 * 2);
    size_t need_A = o;

    // ---- Path B/C layout: ELL ----
    o = 0;
    int* cursor  = (int*)(ws + o);
    int* ovfcntB = cursor + N;
    o = align16(o + ((size_t)N + 1) * 4);
    OvfEdge* ovfB = (OvfEdge*)(ws + o); o = align16(o + (size_t)OVFCAP * sizeof(OvfEdge));
    unsigned* ellB = (unsigned*)(ws + o); o = align16(o + (size_t)N * ELLK * 4);
    size_t need_mid = o;
    unsigned short* mbB = (unsigned short*)(ws + o); o = align16(o + (size_t)M2 * 2);
    size_t need_full = o;

    const int vblocks = ((E + 3) / 4 + 255) / 256;
    const int sblocks = (N * 64 + 255) / 256;
    const int cblocks = (n4 + 255) / 256;
    const int p1blocks = (E + P1_TILE - 1) / P1_TILE;

    if (N <= 65535 && nbuck <= MAXBUCK && ws_size >= need_A) {
        hipMemsetAsync(gcur, 0, ((size_t)nbuck + 1) * 4, stream);
        int bgrid = p1blocks + (n4 + 1023) / 1024;
        build_kernel<<<bgrid, 1024, 0, stream>>>(rows, cols, vals, mat2, mbA, n4,
                                                 gcur, ebuf, ovfcntA, ovfA, E, nbuck, p1blocks);
        spmm_pass_kernel<<<nbuck, 512, 0, stream>>>(gcur, ebuf, mbA, out, N, ovfcntA, ovfA);
        ovf_kernel<<<1, 256, 0, stream>>>(ovfcntA, ovfA, mat2, out);
    } else if (N <= 65535 && ws_size >= need_full) {
        hipMemsetAsync(cursor, 0, ((size_t)N + 1) * 4, stream);
        cvt_kernel<<<cblocks, 256, 0, stream>>>(mat2, mbB, n4);
        scatter_ell_kernel<<<vblocks, 256, 0, stream>>>(rows, cols, vals, cursor, ellB, ovfcntB, ovfB, E);
        spmm_ell_kernel<true><<<sblocks, 256, 0, stream>>>(cursor, ellB, mbB, mat2, out, N);
        ovf_kernel<<<1, 256, 0, stream>>>(ovfcntB, ovfB, mat2, out);
    } else if (N <= 65535 && ws_size >= need_mid) {
        hipMemsetAsync(cursor, 0, ((size_t)N + 1) * 4, stream);
        scatter_ell_kernel<<<vblocks, 256, 0, stream>>>(rows, cols, vals, cursor, ellB, ovfcntB, ovfB, E);
        spmm_ell_kernel<false><<<sblocks, 256, 0, stream>>>(cursor, ellB, mbB, mat2, out, N);
        ovf_kernel<<<1, 256, 0, stream>>>(ovfcntB, ovfB, mat2, out);
    } else {
        hipMemsetAsync(d_out, 0, (size_t)out_size * sizeof(float), stream);
        long long total = (long long)E * 64;
        spmm_atomic_kernel<<<(int)((total + 255) / 256), 256, 0, stream>>>(rows, cols, vals, mat2, out, E);
    }
}

// Round 14
// 162.923 us; speedup vs baseline: 1.2067x; 1.2067x over previous
//
#include <hip/hip_runtime.h>

#define F_DIM   256
#define OVFCAP  8192
#define MAXBUCK 1024
#define BCAP    2560     // bucket capacity (mean 2048, +11 sigma); MUST be <= 512*5
#define P1_TILE 8192     // edges per bucket-build block (1024 thr x 8)
#define NPASS   8        // column passes; 50000/8 cols * 512 B = 3.2 MB < 4 MB L2/XCD
#define RCAP    24       // per-row per-pass LDS slots (lambda = 4)
#define ELLK    64       // fallback path

struct OvfEdge { int r, c; float v; };

__device__ __forceinline__ unsigned short f32_to_bf16(float x) {
    unsigned u = __float_as_uint(x);
    unsigned r = (u + 0x7FFFu + ((u >> 16) & 1u)) >> 16;  // RNE
    return (unsigned short)r;
}

__device__ __forceinline__ void gfma(unsigned e, int lane,
                                     const unsigned short* __restrict__ mb, float4& acc) {
    int   col = (int)(e >> 16);
    float v   = __uint_as_float((e & 0xFFFFu) << 16);
    ushort4 m = ((const ushort4*)(mb + ((long long)col << 8)))[lane];
    acc.x += v * __uint_as_float((unsigned)m.x << 16);
    acc.y += v * __uint_as_float((unsigned)m.y << 16);
    acc.z += v * __uint_as_float((unsigned)m.z << 16);
    acc.w += v * __uint_as_float((unsigned)m.w << 16);
}

// ---------- standalone cvt (fallback path B) ----------
__global__ void cvt_kernel(const float* __restrict__ src,
                           unsigned short* __restrict__ dst, int n4) {
    int t = blockIdx.x * blockDim.x + threadIdx.x;
    if (t >= n4) return;
    float4 f = ((const float4*)src)[t];
    ushort4 o;
    o.x = f32_to_bf16(f.x); o.y = f32_to_bf16(f.y);
    o.z = f32_to_bf16(f.z); o.w = f32_to_bf16(f.w);
    ((ushort4*)dst)[t] = o;
}

// ---------- fused build: blocks [0,p1blocks) bucket edges; rest convert mat_2 ----------
__global__ void __launch_bounds__(1024)
build_kernel(const int* __restrict__ rows, const int* __restrict__ cols,
             const float* __restrict__ vals,
             const float* __restrict__ mat2, unsigned short* __restrict__ mb, int n4,
             int* __restrict__ gcur, int2* __restrict__ ebuf,
             int* __restrict__ ovfcnt, OvfEdge* __restrict__ ovf,
             int E, int nbuck, int p1blocks) {
    __shared__ int s_cnt[MAXBUCK];
    __shared__ int s_base[MAXBUCK];
    __shared__ int s_cur[MAXBUCK];
    const int t = threadIdx.x;
    const int bid = blockIdx.x;

    if (bid >= p1blocks) {                       // ---- cvt part ----
        int i = (bid - p1blocks) * 1024 + t;
        if (i < n4) {
            float4 f = ((const float4*)mat2)[i];
            ushort4 o;
            o.x = f32_to_bf16(f.x); o.y = f32_to_bf16(f.y);
            o.z = f32_to_bf16(f.z); o.w = f32_to_bf16(f.w);
            ((ushort4*)mb)[i] = o;
        }
        return;
    }

    // ---- bucket part ----
    for (int i = t; i < nbuck; i += 1024) { s_cnt[i] = 0; s_cur[i] = 0; }
    __syncthreads();

    const long long e0 = (long long)bid * P1_TILE;
    int4 r4[2], c4[2]; float4 v4[2];
    #pragma unroll
    for (int k = 0; k < 2; ++k) {
        long long i = e0 + (long long)k * 4096 + (long long)t * 4;
        if (i + 3 < E) {
            r4[k] = *(const int4*)(rows + i);
            c4[k] = *(const int4*)(cols + i);
            v4[k] = *(const float4*)(vals + i);
        } else {
            r4[k] = make_int4(-1, -1, -1, -1);
            c4[k] = make_int4(0, 0, 0, 0);
            v4[k] = make_float4(0.f, 0.f, 0.f, 0.f);
            #pragma unroll
            for (int j = 0; j < 4; ++j) {
                long long ii = i + j;
                if (ii < E) {
                    (&r4[k].x)[j] = rows[ii];
                    (&c4[k].x)[j] = cols[ii];
                    (&v4[k].x)[j] = vals[ii];
                }
            }
        }
        #pragma unroll
        for (int j = 0; j < 4; ++j) {
            int rr = (&r4[k].x)[j];
            if (rr >= 0) atomicAdd(&s_cnt[rr >> 6], 1);   // LDS
        }
    }
    __syncthreads();
    for (int i = t; i < nbuck; i += 1024) {
        int c_ = s_cnt[i];
        s_base[i] = c_ ? atomicAdd(&gcur[i], c_) : 0;     // 1 global atomic per (block,bucket)
    }
    __syncthreads();
    #pragma unroll
    for (int k = 0; k < 2; ++k) {
        #pragma unroll
        for (int j = 0; j < 4; ++j) {
            int rr = (&r4[k].x)[j];
            if (rr < 0) continue;
            int cc = (&c4[k].x)[j];
            float vv = (&v4[k].x)[j];
            int b = rr >> 6;
            int sl = s_base[b] + atomicAdd(&s_cur[b], 1); // LDS
            if (sl < BCAP) {
                ebuf[(long long)b * BCAP + sl] =
                    make_int2((int)(((unsigned)cc << 16) | f32_to_bf16(vv)), rr & 63);
            } else {
                int o = atomicAdd(ovfcnt, 1);
                if (o < OVFCAP) { ovf[o].r = rr; ovf[o].c = cc; ovf[o].v = vv; }
            }
        }
    }
}

// ---------- Phase 2: one block per 64-row bucket (R10 structure, max occupancy).
// Edges live in registers (<=5/thread, 512*5 = 2560 = BCAP). Per 6250-col
// (3.2 MB, L2-resident) pass: register-scan bins matching edges into a
// double-buffered LDS ELL; bin(p+1) overlaps compute(p). Compute: full wave
// per row (8 rows/wave), ushort4 gathers batched x4. Owner-reset counters ->
// 1 barrier/pass. LDS 12.8 KB + <=64 VGPR -> 4 blk/CU -> ~100% occupancy,
// all 782 buckets co-resident. ----------
__global__ void __launch_bounds__(512, 8)
spmm_pass_kernel(const int* __restrict__ gcur, const int2* __restrict__ ebuf,
                 const unsigned short* __restrict__ mb,
                 float* __restrict__ out, int N,
                 int* __restrict__ ovfcnt, OvfEdge* __restrict__ ovf) {
    __shared__ unsigned ell_s[2][64 * RCAP];   // 12 KB
    __shared__ int cur_s[2][64];
    const int t = threadIdx.x, b = blockIdx.x;
    const int wid = t >> 6, lane = t & 63;
    const int cnt = min(gcur[b], BCAP);
    const int2* eb = ebuf + (long long)b * BCAP;
    const int passw = (N + NPASS - 1) / NPASS;

    if (t < 128) ((int*)cur_s)[t] = 0;

    // ---- load up to 5 strided edges into registers ----
    unsigned ecol[5]; int erow[5]; int nv = 0;
    #pragma unroll
    for (int k = 0; k < 5; ++k) {
        int j = t + k * 512;
        if (j < cnt) {
            int2 e = eb[j];
            ecol[nv] = (unsigned)e.x;
            erow[nv] = e.y;
            ++nv;
        }
    }
    __syncthreads();   // cur_s zeroed

    auto bin = [&](int p, int buf) {
        const int lo = p * passw;
        #pragma unroll
        for (int k = 0; k < 5; ++k) {
            if (k < nv) {
                int col = (int)(ecol[k] >> 16);
                if ((unsigned)(col - lo) < (unsigned)passw) {
                    int pos = atomicAdd(&cur_s[buf][erow[k]], 1);
                    if (pos < RCAP) {
                        ell_s[buf][erow[k] * RCAP + pos] = ecol[k];
                    } else {
                        int o = atomicAdd(ovfcnt, 1);
                        if (o < OVFCAP) {
                            ovf[o].r = b * 64 + erow[k];
                            ovf[o].c = col;
                            ovf[o].v = __uint_as_float((ecol[k] & 0xFFFFu) << 16);
                        }
                    }
                }
            }
        }
    };

    bin(0, 0);
    __syncthreads();

    float4 acc[8];
    #pragma unroll
    for (int r = 0; r < 8; ++r) acc[r] = make_float4(0.f, 0.f, 0.f, 0.f);

    for (int p = 0; p < NPASS; ++p) {
        const int cur = p & 1, nxt = cur ^ 1;
        if (p + 1 < NPASS) bin(p + 1, nxt);    // LDS/atomic work; overlaps gathers below

        const unsigned pad = (unsigned)(p * passw) << 16;   // v=0, col=window base (hot)
        #pragma unroll
        for (int ri = 0; ri < 8; ++ri) {
            const int rr = wid + (ri << 3);    // wave wid owns rows wid, wid+8, ..., wid+56
            int deg = min(cur_s[cur][rr], RCAP);
            unsigned pk = (lane < deg) ? ell_s[cur][rr * RCAP + lane] : pad;
            int padded = (deg + 3) & ~3;
            for (int j2 = 0; j2 < padded; j2 += 4) {
                ushort4 m[4]; float v[4];
                #pragma unroll
                for (int k = 0; k < 4; ++k) {           // issue 4 independent gathers
                    unsigned e = (unsigned)__shfl((int)pk, j2 + k);
                    v[k] = __uint_as_float((e & 0xFFFFu) << 16);
                    m[k] = ((const ushort4*)(mb + ((long long)(e >> 16) << 8)))[lane];
                }
                #pragma unroll
                for (int k = 0; k < 4; ++k) {           // consume
                    acc[ri].x += v[k] * __uint_as_float((unsigned)m[k].x << 16);
                    acc[ri].y += v[k] * __uint_as_float((unsigned)m[k].y << 16);
                    acc[ri].z += v[k] * __uint_as_float((unsigned)m[k].z << 16);
                    acc[ri].w += v[k] * __uint_as_float((unsigned)m[k].w << 16);
                }
            }
            if (lane == 0) cur_s[cur][rr] = 0;          // owner reset for pass p+2
        }
        __syncthreads();                       // bins(p+1) ready; ell_s[cur]/cur_s[cur] free
    }

    #pragma unroll
    for (int ri = 0; ri < 8; ++ri) {
        const int rr = wid + (ri << 3);
        long long gr = (long long)b * 64 + rr;
        if (gr < N) ((float4*)(out + (gr << 8)))[lane] = acc[ri];
    }
}

// ---------- overflow fixup (expected ~0): f32 atomics ----------
__global__ void ovf_kernel(const int* __restrict__ ovfcnt,
                           const OvfEdge* __restrict__ ovf,
                           const float* __restrict__ mat2,
                           float* __restrict__ out) {
    int cnt = min(*ovfcnt, OVFCAP);
    int lane = threadIdx.x & 63;
    int wid = threadIdx.x >> 6;
    for (int e = wid; e < cnt; e += 4) {
        OvfEdge ed = ovf[e];
        float4 m = ((const float4*)(mat2 + (long long)ed.c * F_DIM))[lane];
        float* dst = out + (long long)ed.r * F_DIM + lane * 4;
        unsafeAtomicAdd(dst + 0, ed.v * m.x);
        unsafeAtomicAdd(dst + 1, ed.v * m.y);
        unsafeAtomicAdd(dst + 2, ed.v * m.z);
        unsafeAtomicAdd(dst + 3, ed.v * m.w);
    }
}

// ---------- Fallback path B/C: global-cursor ELL (R5) ----------
__device__ __forceinline__ void scatter_one(int r, int c, float v,
                                            int* cursor, unsigned* ell,
                                            int* ovfcnt, OvfEdge* ovf) {
    int pos = atomicAdd(&cursor[r], 1);
    if (pos < ELLK) {
        ell[(long long)r * ELLK + pos] = ((unsigned)c << 16) | f32_to_bf16(v);
    } else {
        int o = atomicAdd(ovfcnt, 1);
        if (o < OVFCAP) { ovf[o].r = r; ovf[o].c = c; ovf[o].v = v; }
    }
}

__global__ void scatter_ell_kernel(const int* __restrict__ rows,
                                   const int* __restrict__ cols,
                                   const float* __restrict__ vals,
                                   int* __restrict__ cursor,
                                   unsigned* __restrict__ ell,
                                   int* __restrict__ ovfcnt,
                                   OvfEdge* __restrict__ ovf, int E) {
    int t = blockIdx.x * blockDim.x + threadIdx.x;
    int i0 = t * 4;
    if (i0 + 3 < E) {
        int4   r = *(const int4*)(rows + i0);
        int4   c = *(const int4*)(cols + i0);
        float4 v = *(const float4*)(vals + i0);
        scatter_one(r.x, c.x, v.x, cursor, ell, ovfcnt, ovf);
        scatter_one(r.y, c.y, v.y, cursor, ell, ovfcnt, ovf);
        scatter_one(r.z, c.z, v.z, cursor, ell, ovfcnt, ovf);
        scatter_one(r.w, c.w, v.w, cursor, ell, ovfcnt, ovf);
    } else {
        for (int i = i0; i < E; ++i)
            scatter_one(rows[i], cols[i], vals[i], cursor, ell, ovfcnt, ovf);
    }
}

template <bool BF16MAT>
__global__ void __launch_bounds__(256)
spmm_ell_kernel(const int* __restrict__ cursor,
                const unsigned* __restrict__ ell,
                const unsigned short* __restrict__ mb,
                const float* __restrict__ mat2,
                float* __restrict__ out, int N) {
    int wave = (int)(((long long)blockIdx.x * blockDim.x + threadIdx.x) >> 6);
    int lane = threadIdx.x & 63;
    if (wave >= N) return;
    int deg = min(cursor[wave], ELLK);
    unsigned pk = (lane < deg) ? ell[(long long)wave * ELLK + lane] : 0u;
    float4 acc = make_float4(0.f, 0.f, 0.f, 0.f);
    int padded = (deg + 7) & ~7;
    for (int j = 0; j < padded; j += 8) {
        #pragma unroll
        for (int k = 0; k < 8; ++k) {
            unsigned e = (unsigned)__shfl((int)pk, j + k);
            if (BF16MAT) {
                gfma(e, lane, mb, acc);
            } else {
                int   col = (int)(e >> 16);
                float v   = __uint_as_float((e & 0xFFFFu) << 16);
                float4 m = ((const float4*)(mat2 + ((long long)col << 8)))[lane];
                acc.x += v * m.x; acc.y += v * m.y;
                acc.z += v * m.z; acc.w += v * m.w;
            }
        }
    }
    ((float4*)(out + ((long long)wave << 8)))[lane] = acc;
}

// ---------- last resort: pure atomic SpMM ----------
__global__ void spmm_atomic_kernel(const int* __restrict__ rows,
                                   const int* __restrict__ cols,
                                   const float* __restrict__ vals,
                                   const float* __restrict__ mat2,
                                   float* __restrict__ out, int E) {
    long long gid = (long long)blockIdx.x * blockDim.x + threadIdx.x;
    long long e = gid >> 6;
    int q = (int)(gid & 63);
    if (e >= E) return;
    int r = rows[e]; int c = cols[e]; float v = vals[e];
    float4 m = ((const float4*)(mat2 + (long long)c * F_DIM))[q];
    float* dst = out + (long long)r * F_DIM + q * 4;
    unsafeAtomicAdd(dst + 0, v * m.x);
    unsafeAtomicAdd(dst + 1, v * m.y);
    unsafeAtomicAdd(dst + 2, v * m.z);
    unsafeAtomicAdd(dst + 3, v * m.w);
}

extern "C" void kernel_launch(void* const* d_in, const int* in_sizes, int n_in,
                              void* d_out, int out_size, void* d_ws, size_t ws_size,
                              hipStream_t stream) {
    const int*   indices = (const int*)d_in[0];
    const float* vals    = (const float*)d_in[1];
    const float* mat2    = (const float*)d_in[3];
    float*       out     = (float*)d_out;

    const int E  = in_sizes[1];
    const int N  = out_size / F_DIM;
    const int M2 = in_sizes[3];
    const int n4 = M2 / 4;
    const int* rows = indices;
    const int* cols = indices + E;
    const int nbuck = (N + 63) >> 6;

    auto align16 = [](size_t x) { return (x + 15) & ~(size_t)15; };
    char* ws = (char*)d_ws;

    // ---- Path A layout: bucket ----
    size_t o = 0;
    int* gcur    = (int*)(ws + o);
    int* ovfcntA = gcur + nbuck;
    o = align16(o + ((size_t)nbuck + 1) * 4);
    OvfEdge* ovfA = (OvfEdge*)(ws + o); o = align16(o + (size_t)OVFCAP * sizeof(OvfEdge));
    int2* ebuf = (int2*)(ws + o);       o = align16(o + (size_t)nbuck * BCAP * 8);
    unsigned short* mbA = (unsigned short*)(ws + o); o = align16(o + (size_t)M2 * 2);
    size_t need_A = o;

    // ---- Path B/C layout: ELL ----
    o = 0;
    int* cursor  = (int*)(ws + o);
    int* ovfcntB = cursor + N;
    o = align16(o + ((size_t)N + 1) * 4);
    OvfEdge* ovfB = (OvfEdge*)(ws + o); o = align16(o + (size_t)OVFCAP * sizeof(OvfEdge));
    unsigned* ellB = (unsigned*)(ws + o); o = align16(o + (size_t)N * ELLK * 4);
    size_t need_mid = o;
    unsigned short* mbB = (unsigned short*)(ws + o); o = align16(o + (size_t)M2 * 2);
    size_t need_full = o;

    const int vblocks = ((E + 3) / 4 + 255) / 256;
    const int sblocks = (N * 64 + 255) / 256;
    const int cblocks = (n4 + 255) / 256;
    const int p1blocks = (E + P1_TILE - 1) / P1_TILE;

    if (N <= 65535 && nbuck <= MAXBUCK && ws_size >= need_A) {
        hipMemsetAsync(gcur, 0, ((size_t)nbuck + 1) * 4, stream);
        int bgrid = p1blocks + (n4 + 1023) / 1024;
        build_kernel<<<bgrid, 1024, 0, stream>>>(rows, cols, vals, mat2, mbA, n4,
                                                 gcur, ebuf, ovfcntA, ovfA, E, nbuck, p1blocks);
        spmm_pass_kernel<<<nbuck, 512, 0, stream>>>(gcur, ebuf, mbA, out, N, ovfcntA, ovfA);
        ovf_kernel<<<1, 256, 0, stream>>>(ovfcntA, ovfA, mat2, out);
    } else if (N <= 65535 && ws_size >= need_full) {
        hipMemsetAsync(cursor, 0, ((size_t)N + 1) * 4, stream);
        cvt_kernel<<<cblocks, 256, 0, stream>>>(mat2, mbB, n4);
        scatter_ell_kernel<<<vblocks, 256, 0, stream>>>(rows, cols, vals, cursor, ellB, ovfcntB, ovfB, E);
        spmm_ell_kernel<true><<<sblocks, 256, 0, stream>>>(cursor, ellB, mbB, mat2, out, N);
        ovf_kernel<<<1, 256, 0, stream>>>(ovfcntB, ovfB, mat2, out);
    } else if (N <= 65535 && ws_size >= need_mid) {
        hipMemsetAsync(cursor, 0, ((size_t)N + 1) * 4, stream);
        scatter_ell_kernel<<<vblocks, 256, 0, stream>>>(rows, cols, vals, cursor, ellB, ovfcntB, ovfB, E);
        spmm_ell_kernel<false><<<sblocks, 256, 0, stream>>>(cursor, ellB, mbB, mat2, out, N);
        ovf_kernel<<<1, 256, 0, stream>>>(ovfcntB, ovfB, mat2, out);
    } else {
        hipMemsetAsync(d_out, 0, (size_t)out_size * sizeof(float), stream);
        long long total = (long long)E * 64;
        spmm_atomic_kernel<<<(int)((total + 255) / 256), 256, 0, stream>>>(rows, cols, vals, mat2, out, E);
    }
}

// Round 15
// 144.448 us; speedup vs baseline: 1.3610x; 1.1279x over previous
//
#include <hip/hip_runtime.h>

#define F_DIM   256
#define OVFCAP  8192
#define MAXBUCK 1024
#define BCAP    2560     // bucket capacity (mean 2048, +11 sigma)
#define P1_TILE 8192     // edges per bucket-build block (1024 thr x 8)
#define NPASS   8        // column passes; 50000/8 cols * 512 B = 3.2 MB < 4 MB L2/XCD
#define RCAP    24       // per-row per-pass LDS slots (lambda = 4)
#define ELLK    64       // fallback path

struct OvfEdge { int r, c; float v; };

__device__ __forceinline__ unsigned short f32_to_bf16(float x) {
    unsigned u = __float_as_uint(x);
    unsigned r = (u + 0x7FFFu + ((u >> 16) & 1u)) >> 16;  // RNE
    return (unsigned short)r;
}

__device__ __forceinline__ void gfma(unsigned e, int lane,
                                     const unsigned short* __restrict__ mb, float4& acc) {
    int   col = (int)(e >> 16);
    float v   = __uint_as_float((e & 0xFFFFu) << 16);
    ushort4 m = ((const ushort4*)(mb + ((long long)col << 8)))[lane];
    acc.x += v * __uint_as_float((unsigned)m.x << 16);
    acc.y += v * __uint_as_float((unsigned)m.y << 16);
    acc.z += v * __uint_as_float((unsigned)m.z << 16);
    acc.w += v * __uint_as_float((unsigned)m.w << 16);
}

// ---------- standalone cvt (fallback path B) ----------
__global__ void cvt_kernel(const float* __restrict__ src,
                           unsigned short* __restrict__ dst, int n4) {
    int t = blockIdx.x * blockDim.x + threadIdx.x;
    if (t >= n4) return;
    float4 f = ((const float4*)src)[t];
    ushort4 o;
    o.x = f32_to_bf16(f.x); o.y = f32_to_bf16(f.y);
    o.z = f32_to_bf16(f.z); o.w = f32_to_bf16(f.w);
    ((ushort4*)dst)[t] = o;
}

// ---------- fused build: blocks [0,p1blocks) bucket edges; rest convert mat_2 ----------
__global__ void __launch_bounds__(1024)
build_kernel(const int* __restrict__ rows, const int* __restrict__ cols,
             const float* __restrict__ vals,
             const float* __restrict__ mat2, unsigned short* __restrict__ mb, int n4,
             int* __restrict__ gcur, int2* __restrict__ ebuf,
             int* __restrict__ ovfcnt, OvfEdge* __restrict__ ovf,
             int E, int nbuck, int p1blocks) {
    __shared__ int s_cnt[MAXBUCK];
    __shared__ int s_base[MAXBUCK];
    __shared__ int s_cur[MAXBUCK];
    const int t = threadIdx.x;
    const int bid = blockIdx.x;

    if (bid >= p1blocks) {                       // ---- cvt part ----
        int i = (bid - p1blocks) * 1024 + t;
        if (i < n4) {
            float4 f = ((const float4*)mat2)[i];
            ushort4 o;
            o.x = f32_to_bf16(f.x); o.y = f32_to_bf16(f.y);
            o.z = f32_to_bf16(f.z); o.w = f32_to_bf16(f.w);
            ((ushort4*)mb)[i] = o;
        }
        return;
    }

    // ---- bucket part ----
    for (int i = t; i < nbuck; i += 1024) { s_cnt[i] = 0; s_cur[i] = 0; }
    __syncthreads();

    const long long e0 = (long long)bid * P1_TILE;
    int4 r4[2], c4[2]; float4 v4[2];
    #pragma unroll
    for (int k = 0; k < 2; ++k) {
        long long i = e0 + (long long)k * 4096 + (long long)t * 4;
        if (i + 3 < E) {
            r4[k] = *(const int4*)(rows + i);
            c4[k] = *(const int4*)(cols + i);
            v4[k] = *(const float4*)(vals + i);
        } else {
            r4[k] = make_int4(-1, -1, -1, -1);
            c4[k] = make_int4(0, 0, 0, 0);
            v4[k] = make_float4(0.f, 0.f, 0.f, 0.f);
            #pragma unroll
            for (int j = 0; j < 4; ++j) {
                long long ii = i + j;
                if (ii < E) {
                    (&r4[k].x)[j] = rows[ii];
                    (&c4[k].x)[j] = cols[ii];
                    (&v4[k].x)[j] = vals[ii];
                }
            }
        }
        #pragma unroll
        for (int j = 0; j < 4; ++j) {
            int rr = (&r4[k].x)[j];
            if (rr >= 0) atomicAdd(&s_cnt[rr >> 6], 1);   // LDS
        }
    }
    __syncthreads();
    for (int i = t; i < nbuck; i += 1024) {
        int c_ = s_cnt[i];
        s_base[i] = c_ ? atomicAdd(&gcur[i], c_) : 0;     // 1 global atomic per (block,bucket)
    }
    __syncthreads();
    #pragma unroll
    for (int k = 0; k < 2; ++k) {
        #pragma unroll
        for (int j = 0; j < 4; ++j) {
            int rr = (&r4[k].x)[j];
            if (rr < 0) continue;
            int cc = (&c4[k].x)[j];
            float vv = (&v4[k].x)[j];
            int b = rr >> 6;
            int sl = s_base[b] + atomicAdd(&s_cur[b], 1); // LDS
            if (sl < BCAP) {
                ebuf[(long long)b * BCAP + sl] =
                    make_int2((int)(((unsigned)cc << 16) | f32_to_bf16(vv)), rr & 63);
            } else {
                int o = atomicAdd(ovfcnt, 1);
                if (o < OVFCAP) { ovf[o].r = rr; ovf[o].c = cc; ovf[o].v = vv; }
            }
        }
    }
}

// ---------- Phase 2: one block per 64-row bucket; 8 column passes over L2-resident
// windows; bin(p+1) overlapped with compute(p) via double-buffered LDS ELL;
// explicit 4-deep load batching; __launch_bounds__(512,8). Proven best (R10: 115.6us). ----------
__global__ void __launch_bounds__(512, 8)
spmm_pass_kernel(const int* __restrict__ gcur, const int2* __restrict__ ebuf,
                 const unsigned short* __restrict__ mb,
                 float* __restrict__ out, int N,
                 int* __restrict__ ovfcnt, OvfEdge* __restrict__ ovf) {
    __shared__ int2 eds[BCAP];                 // 20 KB
    __shared__ unsigned ell_s[2][64 * RCAP];   // 12 KB
    __shared__ int cur_s[2][64];
    const int t = threadIdx.x;
    const int b = blockIdx.x;
    const int cnt = min(gcur[b], BCAP);
    const int2* eb = ebuf + (long long)b * BCAP;
    for (int j = t; j < cnt; j += 512) eds[j] = eb[j];
    if (t < 128) ((int*)cur_s)[t] = 0;
    __syncthreads();

    const int passw = (N + NPASS - 1) / NPASS;

    auto bin = [&](int p, int buf) {
        const int lo = p * passw;
        for (int j = t; j < cnt; j += 512) {
            int2 e = eds[j];
            int col = (int)((unsigned)e.x >> 16);
            if ((unsigned)(col - lo) < (unsigned)passw) {
                int pos = atomicAdd(&cur_s[buf][e.y], 1);
                if (pos < RCAP) {
                    ell_s[buf][e.y * RCAP + pos] = (unsigned)e.x;
                } else {
                    int o = atomicAdd(ovfcnt, 1);
                    if (o < OVFCAP) {
                        ovf[o].r = b * 64 + e.y;
                        ovf[o].c = col;
                        ovf[o].v = __uint_as_float(((unsigned)e.x & 0xFFFFu) << 16);
                    }
                }
            }
        }
    };

    bin(0, 0);
    __syncthreads();

    const int wid = t >> 6, lane = t & 63;
    float4 acc[8];
    #pragma unroll
    for (int r = 0; r < 8; ++r) acc[r] = make_float4(0.f, 0.f, 0.f, 0.f);

    for (int p = 0; p < NPASS; ++p) {
        const int cur = p & 1, nxt = cur ^ 1;
        if (p + 1 < NPASS) bin(p + 1, nxt);    // LDS work; overlaps gathers below

        const unsigned pad = (unsigned)(p * passw) << 16;   // v=0, col=window base (hot)
        #pragma unroll
        for (int ri = 0; ri < 8; ++ri) {
            const int rr = wid + (ri << 3);
            int deg = min(cur_s[cur][rr], RCAP);
            unsigned pk = (lane < deg) ? ell_s[cur][rr * RCAP + lane] : pad;
            int padded = (deg + 3) & ~3;
            for (int j2 = 0; j2 < padded; j2 += 4) {
                ushort4 m[4]; float v[4];
                #pragma unroll
                for (int k = 0; k < 4; ++k) {           // issue 4 independent gathers
                    unsigned e = (unsigned)__shfl((int)pk, j2 + k);
                    v[k] = __uint_as_float((e & 0xFFFFu) << 16);
                    m[k] = ((const ushort4*)(mb + ((long long)(e >> 16) << 8)))[lane];
                }
                #pragma unroll
                for (int k = 0; k < 4; ++k) {           // consume
                    acc[ri].x += v[k] * __uint_as_float((unsigned)m[k].x << 16);
                    acc[ri].y += v[k] * __uint_as_float((unsigned)m[k].y << 16);
                    acc[ri].z += v[k] * __uint_as_float((unsigned)m[k].z << 16);
                    acc[ri].w += v[k] * __uint_as_float((unsigned)m[k].w << 16);
                }
            }
        }
        __syncthreads();                       // bins(p+1) ready; ell_s[cur] free
        if (t < 64) cur_s[cur][t] = 0;         // recycle counters for pass p+2
        __syncthreads();
    }

    #pragma unroll
    for (int ri = 0; ri < 8; ++ri) {
        const int rr = wid + (ri << 3);
        long long gr = (long long)b * 64 + rr;
        if (gr < N) ((float4*)(out + (gr << 8)))[lane] = acc[ri];
    }
}

// ---------- overflow fixup (expected ~0): f32 atomics ----------
__global__ void ovf_kernel(const int* __restrict__ ovfcnt,
                           const OvfEdge* __restrict__ ovf,
                           const float* __restrict__ mat2,
                           float* __restrict__ out) {
    int cnt = min(*ovfcnt, OVFCAP);
    int lane = threadIdx.x & 63;
    int wid = threadIdx.x >> 6;
    for (int e = wid; e < cnt; e += 4) {
        OvfEdge ed = ovf[e];
        float4 m = ((const float4*)(mat2 + (long long)ed.c * F_DIM))[lane];
        float* dst = out + (long long)ed.r * F_DIM + lane * 4;
        unsafeAtomicAdd(dst + 0, ed.v * m.x);
        unsafeAtomicAdd(dst + 1, ed.v * m.y);
        unsafeAtomicAdd(dst + 2, ed.v * m.z);
        unsafeAtomicAdd(dst + 3, ed.v * m.w);
    }
}

// ---------- Fallback path B/C: global-cursor ELL (R5) ----------
__device__ __forceinline__ void scatter_one(int r, int c, float v,
                                            int* cursor, unsigned* ell,
                                            int* ovfcnt, OvfEdge* ovf) {
    int pos = atomicAdd(&cursor[r], 1);
    if (pos < ELLK) {
        ell[(long long)r * ELLK + pos] = ((unsigned)c << 16) | f32_to_bf16(v);
    } else {
        int o = atomicAdd(ovfcnt, 1);
        if (o < OVFCAP) { ovf[o].r = r; ovf[o].c = c; ovf[o].v = v; }
    }
}

__global__ void scatter_ell_kernel(const int* __restrict__ rows,
                                   const int* __restrict__ cols,
                                   const float* __restrict__ vals,
                                   int* __restrict__ cursor,
                                   unsigned* __restrict__ ell,
                                   int* __restrict__ ovfcnt,
                                   OvfEdge* __restrict__ ovf, int E) {
    int t = blockIdx.x * blockDim.x + threadIdx.x;
    int i0 = t * 4;
    if (i0 + 3 < E) {
        int4   r = *(const int4*)(rows + i0);
        int4   c = *(const int4*)(cols + i0);
        float4 v = *(const float4*)(vals + i0);
        scatter_one(r.x, c.x, v.x, cursor, ell, ovfcnt, ovf);
        scatter_one(r.y, c.y, v.y, cursor, ell, ovfcnt, ovf);
        scatter_one(r.z, c.z, v.z, cursor, ell, ovfcnt, ovf);
        scatter_one(r.w, c.w, v.w, cursor, ell, ovfcnt, ovf);
    } else {
        for (int i = i0; i < E; ++i)
            scatter_one(rows[i], cols[i], vals[i], cursor, ell, ovfcnt, ovf);
    }
}

template <bool BF16MAT>
__global__ void __launch_bounds__(256)
spmm_ell_kernel(const int* __restrict__ cursor,
                const unsigned* __restrict__ ell,
                const unsigned short* __restrict__ mb,
                const float* __restrict__ mat2,
                float* __restrict__ out, int N) {
    int wave = (int)(((long long)blockIdx.x * blockDim.x + threadIdx.x) >> 6);
    int lane = threadIdx.x & 63;
    if (wave >= N) return;
    int deg = min(cursor[wave], ELLK);
    unsigned pk = (lane < deg) ? ell[(long long)wave * ELLK + lane] : 0u;
    float4 acc = make_float4(0.f, 0.f, 0.f, 0.f);
    int padded = (deg + 7) & ~7;
    for (int j = 0; j < padded; j += 8) {
        #pragma unroll
        for (int k = 0; k < 8; ++k) {
            unsigned e = (unsigned)__shfl((int)pk, j + k);
            if (BF16MAT) {
                gfma(e, lane, mb, acc);
            } else {
                int   col = (int)(e >> 16);
                float v   = __uint_as_float((e & 0xFFFFu) << 16);
                float4 m = ((const float4*)(mat2 + ((long long)col << 8)))[lane];
                acc.x += v * m.x; acc.y += v * m.y;
                acc.z += v * m.z; acc.w += v * m.w;
            }
        }
    }
    ((float4*)(out + ((long long)wave << 8)))[lane] = acc;
}

// ---------- last resort: pure atomic SpMM ----------
__global__ void spmm_atomic_kernel(const int* __restrict__ rows,
                                   const int* __restrict__ cols,
                                   const float* __restrict__ vals,
                                   const float* __restrict__ mat2,
                                   float* __restrict__ out, int E) {
    long long gid = (long long)blockIdx.x * blockDim.x + threadIdx.x;
    long long e = gid >> 6;
    int q = (int)(gid & 63);
    if (e >= E) return;
    int r = rows[e]; int c = cols[e]; float v = vals[e];
    float4 m = ((const float4*)(mat2 + (long long)c * F_DIM))[q];
    float* dst = out + (long long)r * F_DIM + q * 4;
    unsafeAtomicAdd(dst + 0, v * m.x);
    unsafeAtomicAdd(dst + 1, v * m.y);
    unsafeAtomicAdd(dst + 2, v * m.z);
    unsafeAtomicAdd(dst + 3, v * m.w);
}

extern "C" void kernel_launch(void* const* d_in, const int* in_sizes, int n_in,
                              void* d_out, int out_size, void* d_ws, size_t ws_size,
                              hipStream_t stream) {
    const int*   indices = (const int*)d_in[0];
    const float* vals    = (const float*)d_in[1];
    const float* mat2    = (const float*)d_in[3];
    float*       out     = (float*)d_out;

    const int E  = in_sizes[1];
    const int N  = out_size / F_DIM;
    const int M2 = in_sizes[3];
    const int n4 = M2 / 4;
    const int* rows = indices;
    const int* cols = indices + E;
    const int nbuck = (N + 63) >> 6;

    auto align16 = [](size_t x) { return (x + 15) & ~(size_t)15; };
    char* ws = (char*)d_ws;

    // ---- Path A layout: bucket ----
    size_t o = 0;
    int* gcur    = (int*)(ws + o);
    int* ovfcntA = gcur + nbuck;
    o = align16(o + ((size_t)nbuck + 1) * 4);
    OvfEdge* ovfA = (OvfEdge*)(ws + o); o = align16(o + (size_t)OVFCAP * sizeof(OvfEdge));
    int2* ebuf = (int2*)(ws + o);       o = align16(o + (size_t)nbuck * BCAP * 8);
    unsigned short* mbA = (unsigned short*)(ws + o); o = align16(o + (size_t)M2 * 2);
    size_t need_A = o;

    // ---- Path B/C layout: ELL ----
    o = 0;
    int* cursor  = (int*)(ws + o);
    int* ovfcntB = cursor + N;
    o = align16(o + ((size_t)N + 1) * 4);
    OvfEdge* ovfB = (OvfEdge*)(ws + o); o = align16(o + (size_t)OVFCAP * sizeof(OvfEdge));
    unsigned* ellB = (unsigned*)(ws + o); o = align16(o + (size_t)N * ELLK * 4);
    size_t need_mid = o;
    unsigned short* mbB = (unsigned short*)(ws + o); o = align16(o + (size_t)M2 * 2);
    size_t need_full = o;

    const int vblocks = ((E + 3) / 4 + 255) / 256;
    const int sblocks = (N * 64 + 255) / 256;
    const int cblocks = (n4 + 255) / 256;
    const int p1blocks = (E + P1_TILE - 1) / P1_TILE;

    if (N <= 65535 && nbuck <= MAXBUCK && ws_size >= need_A) {
        hipMemsetAsync(gcur, 0, ((size_t)nbuck + 1) * 4, stream);
        int bgrid = p1blocks + (n4 + 1023) / 1024;
        build_kernel<<<bgrid, 1024, 0, stream>>>(rows, cols, vals, mat2, mbA, n4,
                                                 gcur, ebuf, ovfcntA, ovfA, E, nbuck, p1blocks);
        spmm_pass_kernel<<<nbuck, 512, 0, stream>>>(gcur, ebuf, mbA, out, N, ovfcntA, ovfA);
        ovf_kernel<<<1, 256, 0, stream>>>(ovfcntA, ovfA, mat2, out);
    } else if (N <= 65535 && ws_size >= need_full) {
        hipMemsetAsync(cursor, 0, ((size_t)N + 1) * 4, stream);
        cvt_kernel<<<cblocks, 256, 0, stream>>>(mat2, mbB, n4);
        scatter_ell_kernel<<<vblocks, 256, 0, stream>>>(rows, cols, vals, cursor, ellB, ovfcntB, ovfB, E);
        spmm_ell_kernel<true><<<sblocks, 256, 0, stream>>>(cursor, ellB, mbB, mat2, out, N);
        ovf_kernel<<<1, 256, 0, stream>>>(ovfcntB, ovfB, mat2, out);
    } else if (N <= 65535 && ws_size >= need_mid) {
        hipMemsetAsync(cursor, 0, ((size_t)N + 1) * 4, stream);
        scatter_ell_kernel<<<vblocks, 256, 0, stream>>>(rows, cols, vals, cursor, ellB, ovfcntB, ovfB, E);
        spmm_ell_kernel<false><<<sblocks, 256, 0, stream>>>(cursor, ellB, mbB, mat2, out, N);
        ovf_kernel<<<1, 256, 0, stream>>>(ovfcntB, ovfB, mat2, out);
    } else {
        hipMemsetAsync(d_out, 0, (size_t)out_size * sizeof(float), stream);
        long long total = (long long)E * 64;
        spmm_atomic_kernel<<<(int)((total + 255) / 256), 256, 0, stream>>>(rows, cols, vals, mat2, out, E);
    }
}